// Round 2
// baseline (340.735 us; speedup 1.0000x reference)
//
#include <hip/hip_runtime.h>
#include <hip/hip_bf16.h>

#define B_ 256
#define L_ 100
#define F_ 8
#define P_ 4
#define E_ 64
#define H_ 4
#define D_ 64
#define C_ 32
#define V_ 10000
#define TOWER_IN_ 1312
#define LN_EPS 0.001f
#define LCH_ 4    // l's per attention block
#define NCH_ 25   // number of l-chunks
#define ZK_ 40    // padded k-stride for sZt (80B: 16B-aligned, conflict-free)

typedef __attribute__((ext_vector_type(8))) short bf8v;           // 8 bf16 (4 VGPRs)
typedef __attribute__((ext_vector_type(8))) unsigned short us8;   // 8 u16
typedef __attribute__((ext_vector_type(4))) float f4v;            // 4 f32 acc

__device__ __forceinline__ unsigned short f2bf(float x) {
    __hip_bfloat16 h = __float2bfloat16(x);
    return __builtin_bit_cast(unsigned short, h);
}

// raw barrier: LDS-drain + s_barrier, NO vmcnt drain (prefetch loads stay in flight)
#define BARRIER() do { \
    asm volatile("s_waitcnt lgkmcnt(0)" ::: "memory"); \
    __builtin_amdgcn_s_barrier(); \
    asm volatile("" ::: "memory"); \
} while (0)

// ---------------------------------------------------------------------------
// Kernel PRO: fused prologue.
//   blocks [0,400)    : precomp  MT[l,h]=(Qh Kh^T)^T, WT[l,h]=(Vh Lh)^T  (bf16)
//   blocks [400,2352) : prep     transpose tower weights to bf16 [n][k]
//   blocks [2352,2480): zero ubs_acc (replaces hipMemsetAsync)
// ---------------------------------------------------------------------------
__global__ __launch_bounds__(256) void prologue_kernel(
    const float* __restrict__ q_w, const float* __restrict__ k_w,
    const float* __restrict__ v_w, const float* __restrict__ lin_w,
    unsigned short* __restrict__ wsMT, unsigned short* __restrict__ wsWT,
    const float* __restrict__ w1, const float* __restrict__ w2,
    const float* __restrict__ w3,
    unsigned short* __restrict__ Wt1, unsigned short* __restrict__ Wt2,
    unsigned short* __restrict__ Wt3, float* __restrict__ ubs_acc)
{
    __shared__ float sA[64][65];
    __shared__ float sB[64][65];
    const int t = threadIdx.x;
    const int bx = blockIdx.x;

    if (bx < 400) {
        // ---------------- precomp ----------------
        const int l = bx >> 2;
        const int h = bx & 3;
        const size_t obase = (size_t)(l * 4 + h) * 4096;

        for (int i = 0; i < 16; ++i) {
            int idx = t + i * 256;
            int e = idx >> 6, d = idx & 63;
            sA[e][d] = q_w[(l * 64 + e) * 256 + h * 64 + d];
            sB[e][d] = k_w[(l * 64 + e) * 256 + h * 64 + d];
        }
        __syncthreads();
        for (int i = 0; i < 16; ++i) {
            int idx = t + i * 256;
            int o = idx >> 6, e = idx & 63;
            float s = 0.f;
            #pragma unroll 8
            for (int d = 0; d < 64; ++d) s += sA[e][d] * sB[o][d];
            wsMT[obase + idx] = f2bf(s);
        }
        __syncthreads();

        for (int i = 0; i < 16; ++i) {
            int idx = t + i * 256;
            int dd = idx >> 6, oo = idx & 63;
            sB[dd][oo] = lin_w[l * 16384 + (h * 64 + dd) * 64 + oo];
        }
        for (int i = 0; i < 16; ++i) {
            int idx = t + i * 256;
            int e = idx >> 6, d = idx & 63;
            sA[e][d] = v_w[(l * 64 + e) * 256 + h * 64 + d];
        }
        __syncthreads();
        for (int i = 0; i < 16; ++i) {
            int idx = t + i * 256;
            int o = idx >> 6, e = idx & 63;
            float s = 0.f;
            #pragma unroll 8
            for (int d = 0; d < 64; ++d) s += sA[e][d] * sB[d][o];
            wsWT[obase + idx] = f2bf(s);
        }
    } else if (bx < 2352) {
        // ---------------- prep (weight transpose) ----------------
        float (*tile)[65] = sA;   // reuse 32x33 corner of sA
        int bi = bx - 400;
        const float* src; unsigned short* dst; int K, N, tk, tn;
        if (bi < 1312)      { src = w1; dst = Wt1; K = 1312; N = 1024; tk = bi / 32;  tn = bi % 32; }
        else if (bi < 1824) { int i = bi - 1312; src = w2; dst = Wt2; K = 1024; N = 512; tk = i / 16; tn = i % 16; }
        else                { int i = bi - 1824; src = w3; dst = Wt3; K = 512;  N = 256; tk = i / 8;  tn = i % 8; }
        const int k0 = tk * 32, n0 = tn * 32;
        const int rr = t >> 5, cc = t & 31;
        #pragma unroll
        for (int i = 0; i < 4; ++i) {
            int r = rr * 4 + i;
            tile[r][cc] = src[(size_t)(k0 + r) * N + n0 + cc];
        }
        __syncthreads();
        #pragma unroll
        for (int i = 0; i < 4; ++i) {
            int r = rr * 4 + i;
            dst[(size_t)(n0 + r) * K + k0 + cc] = f2bf(tile[cc][r]);
        }
    } else {
        // ---------------- zero ubs_acc ----------------
        const int bi = bx - 2352;                  // 128 blocks x 1024 floats
        float4 z = {0.f, 0.f, 0.f, 0.f};
        *(float4*)(ubs_acc + (size_t)bi * 1024 + t * 4) = z;
    }
}

// ---------------------------------------------------------------------------
// Kernel A: fused attention.  grid = NCH_*32 blocks, 256 threads = 4 waves.
// (unchanged from R1: raw barriers + prefetch + conflict-free gather + pad)
// ---------------------------------------------------------------------------
__global__ __launch_bounds__(256, 3) void attn_kernel(
    const int* __restrict__ ubs_feature, const float* __restrict__ item_tables,
    const unsigned short* __restrict__ wsMT, const unsigned short* __restrict__ wsWT,
    const float* __restrict__ lin_b, const float* __restrict__ ln_g,
    const float* __restrict__ ln_b, float* __restrict__ ubs_acc)
{
    __shared__ __align__(16) unsigned short sUE[64][72];       // rows=b_loc*8+f
    __shared__ __align__(16) unsigned short sT[64][136];       // cols=hl*64+e'
    __shared__ __align__(16) unsigned short sZt[4][64][ZK_];   // [pair][e][k] (k<32 used)
    __shared__ __align__(16) unsigned short sAblk[4][16][32];  // [pair][r][k]
    __shared__ float sLng[64], sLnb[64], sLinb[LCH_][64];

    const int t = threadIdx.x;
    const int c = blockIdx.x >> 5;            // l-chunk 0..24
    const int b0 = (blockIdx.x & 31) * 8;
    const int wv = t >> 6, lane = t & 63, quad = lane >> 4, cl = lane & 15;
    const int role = wv >> 1, hlw = wv & 1;

    const int grow = wv * 16 + (lane >> 2);   // row in [0,64) = b_loc*8 + f
    const int gseg = lane & 3;                // 16-float segment
    const int gb = b0 + (grow >> 3), gf = grow & 7;

    if (t < 64) { sLng[t] = ln_g[t]; sLnb[t] = ln_b[t]; }
    if (t >= 64 && t < 128) {
        #pragma unroll
        for (int li = 0; li < LCH_; ++li)
            sLinb[li][t - 64] = lin_b[(c * LCH_ + li) * 64 + (t - 64)];
    }

    int vidx[LCH_];
    #pragma unroll
    for (int li = 0; li < LCH_; ++li)
        vidx[li] = ubs_feature[(gb * L_ + c * LCH_ + li) * F_ + gf];

    float4 pf[4];
    bf8v bfrag[4][2];

    auto load_bfrag = [&](int lh) {   // lh = l*4 + half*2 + hlw
        const unsigned short* Bsrc = (role == 0 ? wsMT : wsWT) + ((size_t)lh * 4096);
        #pragma unroll
        for (int nt = 0; nt < 4; ++nt)
            #pragma unroll
            for (int k2 = 0; k2 < 2; ++k2)
                bfrag[nt][k2] = *(const bf8v*)(Bsrc + (nt * 16 + cl) * 64 + k2 * 32 + quad * 8);
    };
    auto load_pf = [&](int li) {
        const float* srcp = item_tables + ((size_t)gf * V_ + vidx[li]) * 64 + gseg * 16;
        #pragma unroll
        for (int j = 0; j < 4; ++j) pf[j] = ((const float4*)srcp)[j];
    };
    auto store_ue = [&]() {
        us8 u0, u1;
        u0[0] = f2bf(pf[0].x); u0[1] = f2bf(pf[0].y); u0[2] = f2bf(pf[0].z); u0[3] = f2bf(pf[0].w);
        u0[4] = f2bf(pf[1].x); u0[5] = f2bf(pf[1].y); u0[6] = f2bf(pf[1].z); u0[7] = f2bf(pf[1].w);
        u1[0] = f2bf(pf[2].x); u1[1] = f2bf(pf[2].y); u1[2] = f2bf(pf[2].z); u1[3] = f2bf(pf[2].w);
        u1[4] = f2bf(pf[3].x); u1[5] = f2bf(pf[3].y); u1[6] = f2bf(pf[3].z); u1[7] = f2bf(pf[3].w);
        *(us8*)&sUE[grow][gseg * 16]     = u0;
        *(us8*)&sUE[grow][gseg * 16 + 8] = u1;
    };

    load_pf(0);
    load_bfrag((c * LCH_) * 4 + hlw);
    store_ue();
    BARRIER();

    float lnacc[16];
    #pragma unroll
    for (int i = 0; i < 16; ++i) lnacc[i] = 0.f;

    for (int li = 0; li < LCH_; ++li) {
        const int l = c * LCH_ + li;

        if (li + 1 < LCH_) load_pf(li + 1);

        f4v accO[4];
        #pragma unroll
        for (int nt = 0; nt < 4; ++nt) accO[nt] = {0.f, 0.f, 0.f, 0.f};

        #pragma unroll
        for (int half = 0; half < 2; ++half) {
            #pragma unroll
            for (int m = 0; m < 4; ++m) {
                bf8v a0 = *(const bf8v*)&sUE[m * 16 + cl][quad * 8];
                bf8v a1 = *(const bf8v*)&sUE[m * 16 + cl][32 + quad * 8];
                #pragma unroll
                for (int nt = 0; nt < 4; ++nt) {
                    f4v acc = {0.f, 0.f, 0.f, 0.f};
                    acc = __builtin_amdgcn_mfma_f32_16x16x32_bf16(a0, bfrag[nt][0], acc, 0, 0, 0);
                    acc = __builtin_amdgcn_mfma_f32_16x16x32_bf16(a1, bfrag[nt][1], acc, 0, 0, 0);
                    if (role == 0) {
                        #pragma unroll
                        for (int j = 0; j < 4; ++j)
                            sT[m * 16 + quad * 4 + j][hlw * 64 + nt * 16 + cl] = f2bf(acc[j]);
                    } else {
                        ushort4 zp;
                        zp.x = f2bf(acc[0]); zp.y = f2bf(acc[1]);
                        zp.z = f2bf(acc[2]); zp.w = f2bf(acc[3]);
                        const int k0 = (quad >> 1) * 16 + hlw * 8 + (quad & 1) * 4;
                        *(ushort4*)&sZt[m][nt * 16 + cl][k0] = zp;
                    }
                }
            }
            if (half == 0)            load_bfrag(l * 4 + 2 + hlw);
            else if (li + 1 < LCH_)   load_bfrag((l + 1) * 4 + hlw);
            BARRIER();

            {
                const int p = wv;
                const bool valid = (cl >> 3) == (quad >> 1);
                #pragma unroll
                for (int hl = 0; hl < 2; ++hl) {
                    bf8v a0s = *(const bf8v*)&sT[p * 16 + cl][hl * 64 + quad * 8];
                    bf8v a1s = *(const bf8v*)&sT[p * 16 + cl][hl * 64 + 32 + quad * 8];
                    bf8v u0 = *(const bf8v*)&sUE[p * 16 + cl][quad * 8];
                    bf8v u1 = *(const bf8v*)&sUE[p * 16 + cl][32 + quad * 8];
                    f4v acc = {0.f, 0.f, 0.f, 0.f};
                    acc = __builtin_amdgcn_mfma_f32_16x16x32_bf16(a0s, u0, acc, 0, 0, 0);
                    acc = __builtin_amdgcn_mfma_f32_16x16x32_bf16(a1s, u1, acc, 0, 0, 0);
                    const int kk = hl * 8 + (cl & 7) + (cl >> 3) * 16;
                    #pragma unroll
                    for (int j = 0; j < 4; ++j) {
                        float v = acc[j] * 0.125f;
                        float mx = v;
                        mx = fmaxf(mx, __shfl_xor(mx, 1));
                        mx = fmaxf(mx, __shfl_xor(mx, 2));
                        mx = fmaxf(mx, __shfl_xor(mx, 4));
                        float ex = __expf(v - mx);
                        float sm = ex;
                        sm += __shfl_xor(sm, 1);
                        sm += __shfl_xor(sm, 2);
                        sm += __shfl_xor(sm, 4);
                        float aw = valid ? ex * __builtin_amdgcn_rcpf(sm) : 0.f;
                        sAblk[p][quad * 4 + j][kk] = f2bf(aw);
                    }
                }
            }

            {
                const int p = wv;
                bf8v a0p = *(const bf8v*)&sAblk[p][cl][quad * 8];
                #pragma unroll
                for (int nt = 0; nt < 4; ++nt) {
                    bf8v bz = *(const bf8v*)&sZt[p][nt * 16 + cl][quad * 8];
                    accO[nt] = __builtin_amdgcn_mfma_f32_16x16x32_bf16(a0p, bz, accO[nt], 0, 0, 0);
                }
            }
            BARRIER();
        }

        {
            float x[16];
            #pragma unroll
            for (int nt = 0; nt < 4; ++nt)
                #pragma unroll
                for (int j = 0; j < 4; ++j)
                    x[nt * 4 + j] = accO[nt][j] + sLinb[li][nt * 16 + cl];
            #pragma unroll
            for (int j = 0; j < 4; ++j) {
                float s = x[j] + x[4 + j] + x[8 + j] + x[12 + j];
                #pragma unroll
                for (int m = 1; m < 16; m <<= 1) s += __shfl_xor(s, m);
                float mean = s * (1.f / 64.f);
                float q = 0.f;
                #pragma unroll
                for (int nt = 0; nt < 4; ++nt) { float d = x[nt * 4 + j] - mean; q += d * d; }
                #pragma unroll
                for (int m = 1; m < 16; m <<= 1) q += __shfl_xor(q, m);
                float rst = rsqrtf(q * (1.f / 64.f) + LN_EPS);
                #pragma unroll
                for (int nt = 0; nt < 4; ++nt) {
                    int col = nt * 16 + cl;
                    lnacc[nt * 4 + j] += (x[nt * 4 + j] - mean) * rst * sLng[col] + sLnb[col];
                }
            }
        }

        if (li + 1 < LCH_) {
            store_ue();
            BARRIER();
        }
    }

    #pragma unroll
    for (int j = 0; j < 4; ++j) {
        const int row = wv * 16 + quad * 4 + j;
        const int b = b0 + (row >> 3), f = row & 7;
        #pragma unroll
        for (int nt = 0; nt < 4; ++nt)
            atomicAdd(&ubs_acc[(size_t)b * 512 + f * 64 + nt * 16 + cl], lnacc[nt * 4 + j]);
    }
}

// ---------------------------------------------------------------------------
// Kernel T: fused tower.  grid = 16 blocks x 1024 threads (16 waves).
// Block owns 16 rows end-to-end: X-build -> gemm1+LN+relu -> gemm2+LN+relu ->
// gemm3+LN+relu+dot(w4)+sigmoid.  Activations live in LDS; weights from L2.
// LDS plan (bytes):  sX [16][1320] bf16 @0      (42240)   } overlaid: sH1
//                    sH1[16][1032] bf16 @0      (33024)   } after LN barrier
//                    sH2[16][520]  bf16 @42240  (16640)
//                    sRedS [16][16] f32 @58880, sRedQ @59904
//                    sMean [16]     f32 @60928, sRstd @60992   (total 61056)
// ---------------------------------------------------------------------------
#define TK1 1320
#define TK2 1032
#define TK3 520

__global__ __launch_bounds__(1024) void tower_kernel(
    const float* __restrict__ ubs_acc,
    const int* __restrict__ target_ad, const int* __restrict__ profile_feature,
    const float* __restrict__ context,
    const float* __restrict__ item_tables, const float* __restrict__ profile_tables,
    const unsigned short* __restrict__ Wt1, const unsigned short* __restrict__ Wt2,
    const unsigned short* __restrict__ Wt3,
    const float* __restrict__ b1, const float* __restrict__ g1, const float* __restrict__ bb1,
    const float* __restrict__ b2, const float* __restrict__ g2, const float* __restrict__ bb2,
    const float* __restrict__ b3, const float* __restrict__ g3, const float* __restrict__ bb3,
    const float* __restrict__ w4, const float* __restrict__ b4,
    float* __restrict__ out)
{
    __shared__ __align__(16) char smem[61056];
    unsigned short* sX  = (unsigned short*)smem;            // [16][TK1]
    unsigned short* sH1 = (unsigned short*)smem;            // [16][TK2] overlay
    unsigned short* sH2 = (unsigned short*)(smem + 42240);  // [16][TK3]
    float* sRedS = (float*)(smem + 58880);                  // [16][16]
    float* sRedQ = (float*)(smem + 59904);                  // [16][16]
    float* sMean = (float*)(smem + 60928);                  // [16]
    float* sRstd = (float*)(smem + 60992);                  // [16]

    const int t = threadIdx.x;
    const int wv = t >> 6, lane = t & 63, quad = lane >> 4, cl = lane & 15;
    const int rb = blockIdx.x * 16;

    // ---- stage 0: build X rows (wave w -> row w) ----
    {
        const int r = wv;
        const int gb = rb + r;
        for (int cc = lane; cc < TOWER_IN_; cc += 64) {
            float x;
            if (cc < 512) x = fmaxf(ubs_acc[(size_t)gb * 512 + cc] * 0.01f, 0.f);
            else if (cc < 1024) { int j = cc - 512, f = j >> 6, e = j & 63;
                x = item_tables[((size_t)f * V_ + target_ad[gb * 8 + f]) * 64 + e]; }
            else if (cc < 1280) { int j = cc - 1024, pp = j >> 6, e = j & 63;
                x = profile_tables[((size_t)pp * V_ + profile_feature[gb * 4 + pp]) * 64 + e]; }
            else x = context[gb * 32 + (cc - 1280)];
            sX[r * TK1 + cc] = f2bf(x);
        }
    }
    __syncthreads();

    // ---- stage 1: C1 = X @ W1 + b1, LN, relu -> sH1.  64 cols/wave. ----
    {
        const int n0 = wv * 64;
        f4v acc[4];
        #pragma unroll
        for (int nt = 0; nt < 4; ++nt) acc[nt] = {0.f, 0.f, 0.f, 0.f};
        for (int k0 = 0; k0 < 1312; k0 += 32) {
            bf8v a = *(const bf8v*)&sX[cl * TK1 + k0 + quad * 8];
            #pragma unroll
            for (int nt = 0; nt < 4; ++nt) {
                bf8v b = *(const bf8v*)(Wt1 + (size_t)(n0 + nt * 16 + cl) * 1312 + k0 + quad * 8);
                acc[nt] = __builtin_amdgcn_mfma_f32_16x16x32_bf16(a, b, acc[nt], 0, 0, 0);
            }
        }
        #pragma unroll
        for (int nt = 0; nt < 4; ++nt) {
            float bv = b1[n0 + nt * 16 + cl];
            #pragma unroll
            for (int j = 0; j < 4; ++j) acc[nt][j] += bv;
        }
        #pragma unroll
        for (int j = 0; j < 4; ++j) {
            float s = acc[0][j] + acc[1][j] + acc[2][j] + acc[3][j];
            float q = acc[0][j]*acc[0][j] + acc[1][j]*acc[1][j] + acc[2][j]*acc[2][j] + acc[3][j]*acc[3][j];
            #pragma unroll
            for (int m = 1; m < 16; m <<= 1) { s += __shfl_xor(s, m); q += __shfl_xor(q, m); }
            if (cl == 0) { int row = quad * 4 + j; sRedS[row * 16 + wv] = s; sRedQ[row * 16 + wv] = q; }
        }
        __syncthreads();
        if (t < 16) {
            float s = 0.f, q = 0.f;
            #pragma unroll
            for (int w = 0; w < 16; ++w) { s += sRedS[t * 16 + w]; q += sRedQ[t * 16 + w]; }
            float mean = s * (1.f / 1024.f);
            float var  = q * (1.f / 1024.f) - mean * mean;
            sMean[t] = mean;
            sRstd[t] = rsqrtf(fmaxf(var, 0.f) + LN_EPS);
        }
        __syncthreads();
        #pragma unroll
        for (int nt = 0; nt < 4; ++nt) {
            int col = n0 + nt * 16 + cl;
            float gg = g1[col], bv = bb1[col];
            #pragma unroll
            for (int j = 0; j < 4; ++j) {
                int row = quad * 4 + j;
                float x = (acc[nt][j] - sMean[row]) * sRstd[row] * gg + bv;
                sH1[row * TK2 + col] = f2bf(fmaxf(x, 0.f));   // sX fully read before 1st barrier
            }
        }
    }
    __syncthreads();

    // ---- stage 2: C2 = H1 @ W2 + b2, LN, relu -> sH2.  32 cols/wave. ----
    {
        const int n0 = wv * 32;
        f4v acc[2];
        acc[0] = {0.f, 0.f, 0.f, 0.f}; acc[1] = {0.f, 0.f, 0.f, 0.f};
        for (int k0 = 0; k0 < 1024; k0 += 32) {
            bf8v a = *(const bf8v*)&sH1[cl * TK2 + k0 + quad * 8];
            #pragma unroll
            for (int nt = 0; nt < 2; ++nt) {
                bf8v b = *(const bf8v*)(Wt2 + (size_t)(n0 + nt * 16 + cl) * 1024 + k0 + quad * 8);
                acc[nt] = __builtin_amdgcn_mfma_f32_16x16x32_bf16(a, b, acc[nt], 0, 0, 0);
            }
        }
        #pragma unroll
        for (int nt = 0; nt < 2; ++nt) {
            float bv = b2[n0 + nt * 16 + cl];
            #pragma unroll
            for (int j = 0; j < 4; ++j) acc[nt][j] += bv;
        }
        #pragma unroll
        for (int j = 0; j < 4; ++j) {
            float s = acc[0][j] + acc[1][j];
            float q = acc[0][j]*acc[0][j] + acc[1][j]*acc[1][j];
            #pragma unroll
            for (int m = 1; m < 16; m <<= 1) { s += __shfl_xor(s, m); q += __shfl_xor(q, m); }
            if (cl == 0) { int row = quad * 4 + j; sRedS[row * 16 + wv] = s; sRedQ[row * 16 + wv] = q; }
        }
        __syncthreads();
        if (t < 16) {
            float s = 0.f, q = 0.f;
            #pragma unroll
            for (int w = 0; w < 16; ++w) { s += sRedS[t * 16 + w]; q += sRedQ[t * 16 + w]; }
            float mean = s * (1.f / 512.f);
            float var  = q * (1.f / 512.f) - mean * mean;
            sMean[t] = mean;
            sRstd[t] = rsqrtf(fmaxf(var, 0.f) + LN_EPS);
        }
        __syncthreads();
        #pragma unroll
        for (int nt = 0; nt < 2; ++nt) {
            int col = n0 + nt * 16 + cl;
            float gg = g2[col], bv = bb2[col];
            #pragma unroll
            for (int j = 0; j < 4; ++j) {
                int row = quad * 4 + j;
                float x = (acc[nt][j] - sMean[row]) * sRstd[row] * gg + bv;
                sH2[row * TK3 + col] = f2bf(fmaxf(x, 0.f));
            }
        }
    }
    __syncthreads();

    // ---- stage 3: C3 = H2 @ W3 + b3, LN, relu, dot w4, sigmoid. 16 cols/wave.
    {
        const int n0 = wv * 16;
        f4v acc = {0.f, 0.f, 0.f, 0.f};
        for (int k0 = 0; k0 < 512; k0 += 32) {
            bf8v a = *(const bf8v*)&sH2[cl * TK3 + k0 + quad * 8];
            bf8v b = *(const bf8v*)(Wt3 + (size_t)(n0 + cl) * 512 + k0 + quad * 8);
            acc = __builtin_amdgcn_mfma_f32_16x16x32_bf16(a, b, acc, 0, 0, 0);
        }
        {
            float bv = b3[n0 + cl];
            #pragma unroll
            for (int j = 0; j < 4; ++j) acc[j] += bv;
        }
        #pragma unroll
        for (int j = 0; j < 4; ++j) {
            float s = acc[j];
            float q = acc[j] * acc[j];
            #pragma unroll
            for (int m = 1; m < 16; m <<= 1) { s += __shfl_xor(s, m); q += __shfl_xor(q, m); }
            if (cl == 0) { int row = quad * 4 + j; sRedS[row * 16 + wv] = s; sRedQ[row * 16 + wv] = q; }
        }
        __syncthreads();
        if (t < 16) {
            float s = 0.f, q = 0.f;
            #pragma unroll
            for (int w = 0; w < 16; ++w) { s += sRedS[t * 16 + w]; q += sRedQ[t * 16 + w]; }
            float mean = s * (1.f / 256.f);
            float var  = q * (1.f / 256.f) - mean * mean;
            sMean[t] = mean;
            sRstd[t] = rsqrtf(fmaxf(var, 0.f) + LN_EPS);
        }
        __syncthreads();
        {
            int col = n0 + cl;
            float gg = g3[col], bv = bb3[col], wv4 = w4[col];
            #pragma unroll
            for (int j = 0; j < 4; ++j) {
                int row = quad * 4 + j;
                float h = fmaxf((acc[j] - sMean[row]) * sRstd[row] * gg + bv, 0.f);
                float p = h * wv4;
                #pragma unroll
                for (int m = 1; m < 16; m <<= 1) p += __shfl_xor(p, m);
                if (cl == 0) sRedS[row * 16 + wv] = p;
            }
        }
        __syncthreads();
        if (t < 16) {
            float p = 0.f;
            #pragma unroll
            for (int w = 0; w < 16; ++w) p += sRedS[t * 16 + w];
            out[rb + t] = 1.f / (1.f + expf(-(p + b4[0])));
        }
    }
}

// ---------------------------------------------------------------------------
extern "C" void kernel_launch(void* const* d_in, const int* in_sizes, int n_in,
                              void* d_out, int out_size, void* d_ws, size_t ws_size,
                              hipStream_t stream)
{
    (void)in_sizes; (void)n_in; (void)out_size; (void)ws_size;
    const int*   target_ad       = (const int*)d_in[0];
    const int*   ubs_feature     = (const int*)d_in[1];
    const int*   profile_feature = (const int*)d_in[2];
    const float* context         = (const float*)d_in[3];
    const float* item_tables     = (const float*)d_in[4];
    const float* profile_tables  = (const float*)d_in[5];
    const float* q_w   = (const float*)d_in[6];
    const float* k_w   = (const float*)d_in[7];
    const float* v_w   = (const float*)d_in[8];
    const float* lin_w = (const float*)d_in[9];
    const float* lin_b = (const float*)d_in[10];
    const float* ln_g  = (const float*)d_in[11];
    const float* ln_b  = (const float*)d_in[12];
    const float* t_w1  = (const float*)d_in[13];
    const float* t_b1  = (const float*)d_in[14];
    const float* t_g1  = (const float*)d_in[15];
    const float* t_bb1 = (const float*)d_in[16];
    const float* t_w2  = (const float*)d_in[17];
    const float* t_b2  = (const float*)d_in[18];
    const float* t_g2  = (const float*)d_in[19];
    const float* t_bb2 = (const float*)d_in[20];
    const float* t_w3  = (const float*)d_in[21];
    const float* t_b3  = (const float*)d_in[22];
    const float* t_g3  = (const float*)d_in[23];
    const float* t_bb3 = (const float*)d_in[24];
    const float* t_w4  = (const float*)d_in[25];
    const float* t_b4  = (const float*)d_in[26];

    char* ws = (char*)d_ws;
    unsigned short* wsMT = (unsigned short*)(ws);              //  3,276,800
    unsigned short* wsWT = (unsigned short*)(ws +  3276800);   //  3,276,800
    float* ubs_acc       = (float*)         (ws +  6553600);   //    524,288
    unsigned short* Wt1  = (unsigned short*)(ws +  7077888);   //  2,686,976
    unsigned short* Wt2  = (unsigned short*)(ws +  9764864);   //  1,048,576
    unsigned short* Wt3  = (unsigned short*)(ws + 10813440);   //    262,144 (end 11,075,584)

    prologue_kernel<<<2480, 256, 0, stream>>>(q_w, k_w, v_w, lin_w, wsMT, wsWT,
                                              t_w1, t_w2, t_w3, Wt1, Wt2, Wt3, ubs_acc);
    attn_kernel<<<NCH_ * 32, 256, 0, stream>>>(ubs_feature, item_tables, wsMT, wsWT,
                                               lin_b, ln_g, ln_b, ubs_acc);
    tower_kernel<<<16, 1024, 0, stream>>>(ubs_acc, target_ad, profile_feature, context,
                                          item_tables, profile_tables, Wt1, Wt2, Wt3,
                                          t_b1, t_g1, t_bb1, t_b2, t_g2, t_bb2,
                                          t_b3, t_g3, t_bb3, t_w4, t_b4, (float*)d_out);
}

// Round 3
// 265.607 us; speedup vs baseline: 1.2829x; 1.2829x over previous
//
#include <hip/hip_runtime.h>
#include <hip/hip_bf16.h>

#define B_ 256
#define L_ 100
#define F_ 8
#define P_ 4
#define E_ 64
#define H_ 4
#define D_ 64
#define C_ 32
#define V_ 10000
#define TOWER_IN_ 1312
#define LN_EPS 0.001f
#define LCH_ 4    // l's per attention block
#define NCH_ 25   // number of l-chunks
#define ZK_ 40    // padded k-stride for sZt (80B: 16B-aligned, conflict-free)

typedef __attribute__((ext_vector_type(8))) short bf8v;           // 8 bf16 (4 VGPRs)
typedef __attribute__((ext_vector_type(8))) unsigned short us8;   // 8 u16
typedef __attribute__((ext_vector_type(4))) float f4v;            // 4 f32 acc

__device__ __forceinline__ unsigned short f2bf(float x) {
    __hip_bfloat16 h = __float2bfloat16(x);
    return __builtin_bit_cast(unsigned short, h);
}

// raw barrier: LDS-drain + s_barrier, NO vmcnt drain (prefetch loads stay in flight)
#define BARRIER() do { \
    asm volatile("s_waitcnt lgkmcnt(0)" ::: "memory"); \
    __builtin_amdgcn_s_barrier(); \
    asm volatile("" ::: "memory"); \
} while (0)

// ---------------------------------------------------------------------------
// Kernel PRO: fused prologue.
//   blocks [0,400)    : precomp (register-tiled f32): MT[l,h]=(Qh Kh^T)^T,
//                       WT[l,h]=(Vh Lh)^T  -> bf16
//   blocks [400,2352) : prep: transpose tower weights to bf16 [n][k]
//   blocks [2352,2480): zero ubs_acc
// ---------------------------------------------------------------------------
__global__ __launch_bounds__(256) void prologue_kernel(
    const float* __restrict__ q_w, const float* __restrict__ k_w,
    const float* __restrict__ v_w, const float* __restrict__ lin_w,
    unsigned short* __restrict__ wsMT, unsigned short* __restrict__ wsWT,
    const float* __restrict__ w1, const float* __restrict__ w2,
    const float* __restrict__ w3,
    unsigned short* __restrict__ Wt1, unsigned short* __restrict__ Wt2,
    unsigned short* __restrict__ Wt3, float* __restrict__ ubs_acc)
{
    __shared__ float sA[64][68];   // stride 68 f32: 16B-aligned rows
    __shared__ float sB[64][68];
    const int t = threadIdx.x;
    const int bx = blockIdx.x;

    if (bx < 400) {
        // ---------------- precomp, 4x4 register tile, float4 k-chunks -------
        const int l = bx >> 2;
        const int h = bx & 3;
        const size_t obase = (size_t)(l * 4 + h) * 4096;
        const int te = t & 15, to = t >> 4;       // e-tile {te+16i}, o-tile {to+16j}

        for (int i = 0; i < 16; ++i) {
            int idx = t + i * 256;
            int e = idx >> 6, d = idx & 63;
            sA[e][d] = q_w[(l * 64 + e) * 256 + h * 64 + d];
            sB[e][d] = k_w[(l * 64 + e) * 256 + h * 64 + d];
        }
        __syncthreads();
        {
            float acc[4][4];
            #pragma unroll
            for (int i = 0; i < 4; ++i)
                #pragma unroll
                for (int j = 0; j < 4; ++j) acc[i][j] = 0.f;
            for (int d0 = 0; d0 < 64; d0 += 4) {
                float4 a4[4], b4[4];
                #pragma unroll
                for (int i = 0; i < 4; ++i) a4[i] = *(const float4*)&sA[te + 16 * i][d0];
                #pragma unroll
                for (int j = 0; j < 4; ++j) b4[j] = *(const float4*)&sB[to + 16 * j][d0];
                #pragma unroll
                for (int i = 0; i < 4; ++i)
                    #pragma unroll
                    for (int j = 0; j < 4; ++j) {
                        acc[i][j] += a4[i].x * b4[j].x;
                        acc[i][j] += a4[i].y * b4[j].y;
                        acc[i][j] += a4[i].z * b4[j].z;
                        acc[i][j] += a4[i].w * b4[j].w;
                    }
            }
            #pragma unroll
            for (int j = 0; j < 4; ++j)
                #pragma unroll
                for (int i = 0; i < 4; ++i)
                    wsMT[obase + (to + 16 * j) * 64 + (te + 16 * i)] = f2bf(acc[i][j]);
        }
        __syncthreads();

        // restage: sA = V[e][d], sB[o][d] = Lh[d][o]  (transposed stage)
        for (int i = 0; i < 16; ++i) {
            int idx = t + i * 256;
            int e = idx >> 6, d = idx & 63;
            sA[e][d] = v_w[(l * 64 + e) * 256 + h * 64 + d];
            int oo = idx & 63, dd = idx >> 6;
            sB[oo][dd] = lin_w[l * 16384 + (h * 64 + dd) * 64 + oo];
        }
        __syncthreads();
        {
            float acc[4][4];
            #pragma unroll
            for (int i = 0; i < 4; ++i)
                #pragma unroll
                for (int j = 0; j < 4; ++j) acc[i][j] = 0.f;
            for (int d0 = 0; d0 < 64; d0 += 4) {
                float4 a4[4], b4[4];
                #pragma unroll
                for (int i = 0; i < 4; ++i) a4[i] = *(const float4*)&sA[te + 16 * i][d0];
                #pragma unroll
                for (int j = 0; j < 4; ++j) b4[j] = *(const float4*)&sB[to + 16 * j][d0];
                #pragma unroll
                for (int i = 0; i < 4; ++i)
                    #pragma unroll
                    for (int j = 0; j < 4; ++j) {
                        acc[i][j] += a4[i].x * b4[j].x;
                        acc[i][j] += a4[i].y * b4[j].y;
                        acc[i][j] += a4[i].z * b4[j].z;
                        acc[i][j] += a4[i].w * b4[j].w;
                    }
            }
            #pragma unroll
            for (int j = 0; j < 4; ++j)
                #pragma unroll
                for (int i = 0; i < 4; ++i)
                    wsWT[obase + (to + 16 * j) * 64 + (te + 16 * i)] = f2bf(acc[i][j]);
        }
    } else if (bx < 2352) {
        // ---------------- prep (weight transpose) ----------------
        float (*tile)[33] = (float (*)[33])sA;
        int bi = bx - 400;
        const float* src; unsigned short* dst; int K, N, tk, tn;
        if (bi < 1312)      { src = w1; dst = Wt1; K = 1312; N = 1024; tk = bi / 32;  tn = bi % 32; }
        else if (bi < 1824) { int i = bi - 1312; src = w2; dst = Wt2; K = 1024; N = 512; tk = i / 16; tn = i % 16; }
        else                { int i = bi - 1824; src = w3; dst = Wt3; K = 512;  N = 256; tk = i / 8;  tn = i % 8; }
        const int k0 = tk * 32, n0 = tn * 32;
        const int rr = t >> 5, cc = t & 31;
        #pragma unroll
        for (int i = 0; i < 4; ++i) {
            int r = rr * 4 + i;
            tile[r][cc] = src[(size_t)(k0 + r) * N + n0 + cc];
        }
        __syncthreads();
        #pragma unroll
        for (int i = 0; i < 4; ++i) {
            int r = rr * 4 + i;
            dst[(size_t)(n0 + r) * K + k0 + cc] = f2bf(tile[cc][r]);
        }
    } else {
        // ---------------- zero ubs_acc ----------------
        const int bi = bx - 2352;                  // 128 blocks x 1024 floats
        float4 z = {0.f, 0.f, 0.f, 0.f};
        *(float4*)(ubs_acc + (size_t)bi * 1024 + t * 4) = z;
    }
}

// ---------------------------------------------------------------------------
// Kernel A: fused attention.  grid = NCH_*32 blocks, 256 threads = 4 waves.
// (unchanged from R1)
// ---------------------------------------------------------------------------
__global__ __launch_bounds__(256, 3) void attn_kernel(
    const int* __restrict__ ubs_feature, const float* __restrict__ item_tables,
    const unsigned short* __restrict__ wsMT, const unsigned short* __restrict__ wsWT,
    const float* __restrict__ lin_b, const float* __restrict__ ln_g,
    const float* __restrict__ ln_b, float* __restrict__ ubs_acc)
{
    __shared__ __align__(16) unsigned short sUE[64][72];       // rows=b_loc*8+f
    __shared__ __align__(16) unsigned short sT[64][136];       // cols=hl*64+e'
    __shared__ __align__(16) unsigned short sZt[4][64][ZK_];   // [pair][e][k] (k<32 used)
    __shared__ __align__(16) unsigned short sAblk[4][16][32];  // [pair][r][k]
    __shared__ float sLng[64], sLnb[64], sLinb[LCH_][64];

    const int t = threadIdx.x;
    const int c = blockIdx.x >> 5;            // l-chunk 0..24
    const int b0 = (blockIdx.x & 31) * 8;
    const int wv = t >> 6, lane = t & 63, quad = lane >> 4, cl = lane & 15;
    const int role = wv >> 1, hlw = wv & 1;

    const int grow = wv * 16 + (lane >> 2);   // row in [0,64) = b_loc*8 + f
    const int gseg = lane & 3;                // 16-float segment
    const int gb = b0 + (grow >> 3), gf = grow & 7;

    if (t < 64) { sLng[t] = ln_g[t]; sLnb[t] = ln_b[t]; }
    if (t >= 64 && t < 128) {
        #pragma unroll
        for (int li = 0; li < LCH_; ++li)
            sLinb[li][t - 64] = lin_b[(c * LCH_ + li) * 64 + (t - 64)];
    }

    int vidx[LCH_];
    #pragma unroll
    for (int li = 0; li < LCH_; ++li)
        vidx[li] = ubs_feature[(gb * L_ + c * LCH_ + li) * F_ + gf];

    float4 pf[4];
    bf8v bfrag[4][2];

    auto load_bfrag = [&](int lh) {   // lh = l*4 + half*2 + hlw
        const unsigned short* Bsrc = (role == 0 ? wsMT : wsWT) + ((size_t)lh * 4096);
        #pragma unroll
        for (int nt = 0; nt < 4; ++nt)
            #pragma unroll
            for (int k2 = 0; k2 < 2; ++k2)
                bfrag[nt][k2] = *(const bf8v*)(Bsrc + (nt * 16 + cl) * 64 + k2 * 32 + quad * 8);
    };
    auto load_pf = [&](int li) {
        const float* srcp = item_tables + ((size_t)gf * V_ + vidx[li]) * 64 + gseg * 16;
        #pragma unroll
        for (int j = 0; j < 4; ++j) pf[j] = ((const float4*)srcp)[j];
    };
    auto store_ue = [&]() {
        us8 u0, u1;
        u0[0] = f2bf(pf[0].x); u0[1] = f2bf(pf[0].y); u0[2] = f2bf(pf[0].z); u0[3] = f2bf(pf[0].w);
        u0[4] = f2bf(pf[1].x); u0[5] = f2bf(pf[1].y); u0[6] = f2bf(pf[1].z); u0[7] = f2bf(pf[1].w);
        u1[0] = f2bf(pf[2].x); u1[1] = f2bf(pf[2].y); u1[2] = f2bf(pf[2].z); u1[3] = f2bf(pf[2].w);
        u1[4] = f2bf(pf[3].x); u1[5] = f2bf(pf[3].y); u1[6] = f2bf(pf[3].z); u1[7] = f2bf(pf[3].w);
        *(us8*)&sUE[grow][gseg * 16]     = u0;
        *(us8*)&sUE[grow][gseg * 16 + 8] = u1;
    };

    load_pf(0);
    load_bfrag((c * LCH_) * 4 + hlw);
    store_ue();
    BARRIER();

    float lnacc[16];
    #pragma unroll
    for (int i = 0; i < 16; ++i) lnacc[i] = 0.f;

    for (int li = 0; li < LCH_; ++li) {
        const int l = c * LCH_ + li;

        if (li + 1 < LCH_) load_pf(li + 1);

        f4v accO[4];
        #pragma unroll
        for (int nt = 0; nt < 4; ++nt) accO[nt] = {0.f, 0.f, 0.f, 0.f};

        #pragma unroll
        for (int half = 0; half < 2; ++half) {
            #pragma unroll
            for (int m = 0; m < 4; ++m) {
                bf8v a0 = *(const bf8v*)&sUE[m * 16 + cl][quad * 8];
                bf8v a1 = *(const bf8v*)&sUE[m * 16 + cl][32 + quad * 8];
                #pragma unroll
                for (int nt = 0; nt < 4; ++nt) {
                    f4v acc = {0.f, 0.f, 0.f, 0.f};
                    acc = __builtin_amdgcn_mfma_f32_16x16x32_bf16(a0, bfrag[nt][0], acc, 0, 0, 0);
                    acc = __builtin_amdgcn_mfma_f32_16x16x32_bf16(a1, bfrag[nt][1], acc, 0, 0, 0);
                    if (role == 0) {
                        #pragma unroll
                        for (int j = 0; j < 4; ++j)
                            sT[m * 16 + quad * 4 + j][hlw * 64 + nt * 16 + cl] = f2bf(acc[j]);
                    } else {
                        ushort4 zp;
                        zp.x = f2bf(acc[0]); zp.y = f2bf(acc[1]);
                        zp.z = f2bf(acc[2]); zp.w = f2bf(acc[3]);
                        const int k0 = (quad >> 1) * 16 + hlw * 8 + (quad & 1) * 4;
                        *(ushort4*)&sZt[m][nt * 16 + cl][k0] = zp;
                    }
                }
            }
            if (half == 0)            load_bfrag(l * 4 + 2 + hlw);
            else if (li + 1 < LCH_)   load_bfrag((l + 1) * 4 + hlw);
            BARRIER();

            {
                const int p = wv;
                const bool valid = (cl >> 3) == (quad >> 1);
                #pragma unroll
                for (int hl = 0; hl < 2; ++hl) {
                    bf8v a0s = *(const bf8v*)&sT[p * 16 + cl][hl * 64 + quad * 8];
                    bf8v a1s = *(const bf8v*)&sT[p * 16 + cl][hl * 64 + 32 + quad * 8];
                    bf8v u0 = *(const bf8v*)&sUE[p * 16 + cl][quad * 8];
                    bf8v u1 = *(const bf8v*)&sUE[p * 16 + cl][32 + quad * 8];
                    f4v acc = {0.f, 0.f, 0.f, 0.f};
                    acc = __builtin_amdgcn_mfma_f32_16x16x32_bf16(a0s, u0, acc, 0, 0, 0);
                    acc = __builtin_amdgcn_mfma_f32_16x16x32_bf16(a1s, u1, acc, 0, 0, 0);
                    const int kk = hl * 8 + (cl & 7) + (cl >> 3) * 16;
                    #pragma unroll
                    for (int j = 0; j < 4; ++j) {
                        float v = acc[j] * 0.125f;
                        float mx = v;
                        mx = fmaxf(mx, __shfl_xor(mx, 1));
                        mx = fmaxf(mx, __shfl_xor(mx, 2));
                        mx = fmaxf(mx, __shfl_xor(mx, 4));
                        float ex = __expf(v - mx);
                        float sm = ex;
                        sm += __shfl_xor(sm, 1);
                        sm += __shfl_xor(sm, 2);
                        sm += __shfl_xor(sm, 4);
                        float aw = valid ? ex * __builtin_amdgcn_rcpf(sm) : 0.f;
                        sAblk[p][quad * 4 + j][kk] = f2bf(aw);
                    }
                }
            }

            {
                const int p = wv;
                bf8v a0p = *(const bf8v*)&sAblk[p][cl][quad * 8];
                #pragma unroll
                for (int nt = 0; nt < 4; ++nt) {
                    bf8v bz = *(const bf8v*)&sZt[p][nt * 16 + cl][quad * 8];
                    accO[nt] = __builtin_amdgcn_mfma_f32_16x16x32_bf16(a0p, bz, accO[nt], 0, 0, 0);
                }
            }
            BARRIER();
        }

        {
            float x[16];
            #pragma unroll
            for (int nt = 0; nt < 4; ++nt)
                #pragma unroll
                for (int j = 0; j < 4; ++j)
                    x[nt * 4 + j] = accO[nt][j] + sLinb[li][nt * 16 + cl];
            #pragma unroll
            for (int j = 0; j < 4; ++j) {
                float s = x[j] + x[4 + j] + x[8 + j] + x[12 + j];
                #pragma unroll
                for (int m = 1; m < 16; m <<= 1) s += __shfl_xor(s, m);
                float mean = s * (1.f / 64.f);
                float q = 0.f;
                #pragma unroll
                for (int nt = 0; nt < 4; ++nt) { float d = x[nt * 4 + j] - mean; q += d * d; }
                #pragma unroll
                for (int m = 1; m < 16; m <<= 1) q += __shfl_xor(q, m);
                float rst = rsqrtf(q * (1.f / 64.f) + LN_EPS);
                #pragma unroll
                for (int nt = 0; nt < 4; ++nt) {
                    int col = nt * 16 + cl;
                    lnacc[nt * 4 + j] += (x[nt * 4 + j] - mean) * rst * sLng[col] + sLnb[col];
                }
            }
        }

        if (li + 1 < LCH_) {
            store_ue();
            BARRIER();
        }
    }

    #pragma unroll
    for (int j = 0; j < 4; ++j) {
        const int row = wv * 16 + quad * 4 + j;
        const int b = b0 + (row >> 3), f = row & 7;
        #pragma unroll
        for (int nt = 0; nt < 4; ++nt)
            atomicAdd(&ubs_acc[(size_t)b * 512 + f * 64 + nt * 16 + cl], lnacc[nt * 4 + j]);
    }
}

// ---------------------------------------------------------------------------
// Kernel R: ubs = relu(acc/L) and gather concat -> X bf16 [256][1312].
// Extra block (blockIdx.x == B_) zeroes the LN stats buffers.
// ---------------------------------------------------------------------------
__global__ __launch_bounds__(256) void reduceX_kernel(
    const float* __restrict__ ubs_acc,
    const int* __restrict__ target_ad, const int* __restrict__ profile_feature,
    const float* __restrict__ context,
    const float* __restrict__ item_tables, const float* __restrict__ profile_tables,
    unsigned short* __restrict__ X, float* __restrict__ statsAll)
{
    const int b = blockIdx.x, t = threadIdx.x;
    if (b == B_) {            // zero stats1 (512 f32) + stats2 (512 f32)
        float4 z = {0.f, 0.f, 0.f, 0.f};
        ((float4*)statsAll)[t] = z;
        return;
    }
    const float2 v = *(const float2*)(ubs_acc + (size_t)b * 512 + t * 2);
    X[b * TOWER_IN_ + t * 2]     = f2bf(fmaxf(v.x * 0.01f, 0.f));
    X[b * TOWER_IN_ + t * 2 + 1] = f2bf(fmaxf(v.y * 0.01f, 0.f));
    for (int cc = 512 + t; cc < TOWER_IN_; cc += 256) {
        float x;
        if (cc < 1024) { int j = cc - 512, f = j >> 6, e = j & 63;
            x = item_tables[((size_t)f * V_ + target_ad[b * 8 + f]) * 64 + e]; }
        else if (cc < 1280) { int j = cc - 1024, pp = j >> 6, e = j & 63;
            x = profile_tables[((size_t)pp * V_ + profile_feature[b * 4 + pp]) * 64 + e]; }
        else x = context[b * 32 + (cc - 1280)];
        X[b * TOWER_IN_ + cc] = f2bf(x);
    }
}

// ---------------------------------------------------------------------------
// Kernel G: bf16 MFMA GEMM  C[m][n] = A[m][:K].Bw[n][:K] + bias[n], f32 out.
// Epilogue: per-row partial (sum, sumsq) atomicAdd into stats (if non-null).
// grid = (N/64, M/16), 256 threads (4 waves; wave = 16-col subtile)
// ---------------------------------------------------------------------------
__global__ __launch_bounds__(256) void gemm_kernel(
    const unsigned short* __restrict__ A, const unsigned short* __restrict__ Bw,
    const float* __restrict__ bias, float* __restrict__ C, int K, int N,
    float* __restrict__ stats)
{
    const int t = threadIdx.x;
    const int wv = t >> 6, lane = t & 63, quad = lane >> 4, cl = lane & 15;
    const int n0 = blockIdx.x * 64 + wv * 16;
    const int m0 = blockIdx.y * 16;
    f4v acc0 = {0.f, 0.f, 0.f, 0.f};
    f4v acc1 = {0.f, 0.f, 0.f, 0.f};
    const unsigned short* arow = A + (size_t)(m0 + cl) * K + quad * 8;
    const unsigned short* brow = Bw + (size_t)(n0 + cl) * K + quad * 8;
    int k0 = 0;
    #pragma unroll 2
    for (; k0 + 64 <= K; k0 += 64) {
        bf8v a0 = *(const bf8v*)(arow + k0);
        bf8v b0 = *(const bf8v*)(brow + k0);
        bf8v a1 = *(const bf8v*)(arow + k0 + 32);
        bf8v b1 = *(const bf8v*)(brow + k0 + 32);
        acc0 = __builtin_amdgcn_mfma_f32_16x16x32_bf16(a0, b0, acc0, 0, 0, 0);
        acc1 = __builtin_amdgcn_mfma_f32_16x16x32_bf16(a1, b1, acc1, 0, 0, 0);
    }
    if (k0 < K) {
        bf8v a = *(const bf8v*)(arow + k0);
        bf8v b = *(const bf8v*)(brow + k0);
        acc0 = __builtin_amdgcn_mfma_f32_16x16x32_bf16(a, b, acc0, 0, 0, 0);
    }
    float bv = bias[n0 + cl];
    float cj[4];
    #pragma unroll
    for (int j = 0; j < 4; ++j) {
        cj[j] = acc0[j] + acc1[j] + bv;
        C[(size_t)(m0 + quad * 4 + j) * N + n0 + cl] = cj[j];
    }
    if (stats) {
        #pragma unroll
        for (int j = 0; j < 4; ++j) {
            float s = cj[j], q = cj[j] * cj[j];
            #pragma unroll
            for (int m = 1; m < 16; m <<= 1) { s += __shfl_xor(s, m); q += __shfl_xor(q, m); }
            if (cl == 0) {
                const int row = m0 + quad * 4 + j;
                atomicAdd(&stats[row * 2], s);
                atomicAdd(&stats[row * 2 + 1], q);
            }
        }
    }
}

// ---------------------------------------------------------------------------
// Kernel N: elementwise LN-apply + ReLU -> bf16, using precomputed row stats.
// grid = 256 (one row per block), 256 threads.
// ---------------------------------------------------------------------------
__global__ __launch_bounds__(256) void lnapply_kernel(
    const float* __restrict__ C, const float* __restrict__ stats,
    const float* __restrict__ g, const float* __restrict__ bb,
    unsigned short* __restrict__ Hx, int N, float invN)
{
    const int b = blockIdx.x, t = threadIdx.x;
    const float s = stats[b * 2], q = stats[b * 2 + 1];
    const float mean = s * invN;
    const float var  = q * invN - mean * mean;
    const float rst  = rsqrtf(fmaxf(var, 0.f) + LN_EPS);
    for (int j = t * 4; j < N; j += 1024) {
        float4 x = *(const float4*)(C + (size_t)b * N + j);
        ushort4 o;
        o.x = f2bf(fmaxf((x.x - mean) * rst * g[j]     + bb[j],     0.f));
        o.y = f2bf(fmaxf((x.y - mean) * rst * g[j + 1] + bb[j + 1], 0.f));
        o.z = f2bf(fmaxf((x.z - mean) * rst * g[j + 2] + bb[j + 2], 0.f));
        o.w = f2bf(fmaxf((x.w - mean) * rst * g[j + 3] + bb[j + 3], 0.f));
        *(ushort4*)(Hx + (size_t)b * N + j) = o;
    }
}

// ---------------------------------------------------------------------------
// block-wide sum over 256 threads (4 waves)
// ---------------------------------------------------------------------------
__device__ __forceinline__ float block_reduce_sum(float v, float* sRed) {
    #pragma unroll
    for (int m = 1; m < 64; m <<= 1) v += __shfl_xor(v, m, 64);
    int wave = threadIdx.x >> 6, lane = threadIdx.x & 63;
    __syncthreads();
    if (lane == 0) sRed[wave] = v;
    __syncthreads();
    return sRed[0] + sRed[1] + sRed[2] + sRed[3];
}

// ---------------------------------------------------------------------------
// Kernel F: final LN + ReLU + dot(w4) + sigmoid.  grid = 256.
// ---------------------------------------------------------------------------
__global__ __launch_bounds__(256) void final_kernel(
    const float* __restrict__ C3, const float* __restrict__ g3,
    const float* __restrict__ bb3, const float* __restrict__ w4,
    const float* __restrict__ b4, float* __restrict__ out)
{
    __shared__ float sRed[4];
    const int b = blockIdx.x, t = threadIdx.x;
    float x = C3[b * 256 + t];
    float s = block_reduce_sum(x, sRed);
    float mean = s * (1.f / 256.f);
    float d = x - mean;
    __syncthreads();
    float q = block_reduce_sum(d * d, sRed);
    float rst = rsqrtf(q * (1.f / 256.f) + LN_EPS);
    float h = fmaxf(d * rst * g3[t] + bb3[t], 0.f);
    __syncthreads();
    float p = block_reduce_sum(h * w4[t], sRed);
    if (t == 0) out[b] = 1.f / (1.f + expf(-(p + b4[0])));
}

// ---------------------------------------------------------------------------
extern "C" void kernel_launch(void* const* d_in, const int* in_sizes, int n_in,
                              void* d_out, int out_size, void* d_ws, size_t ws_size,
                              hipStream_t stream)
{
    (void)in_sizes; (void)n_in; (void)out_size; (void)ws_size;
    const int*   target_ad       = (const int*)d_in[0];
    const int*   ubs_feature     = (const int*)d_in[1];
    const int*   profile_feature = (const int*)d_in[2];
    const float* context         = (const float*)d_in[3];
    const float* item_tables     = (const float*)d_in[4];
    const float* profile_tables  = (const float*)d_in[5];
    const float* q_w   = (const float*)d_in[6];
    const float* k_w   = (const float*)d_in[7];
    const float* v_w   = (const float*)d_in[8];
    const float* lin_w = (const float*)d_in[9];
    const float* lin_b = (const float*)d_in[10];
    const float* ln_g  = (const float*)d_in[11];
    const float* ln_b  = (const float*)d_in[12];
    const float* t_w1  = (const float*)d_in[13];
    const float* t_b1  = (const float*)d_in[14];
    const float* t_g1  = (const float*)d_in[15];
    const float* t_bb1 = (const float*)d_in[16];
    const float* t_w2  = (const float*)d_in[17];
    const float* t_b2  = (const float*)d_in[18];
    const float* t_g2  = (const float*)d_in[19];
    const float* t_bb2 = (const float*)d_in[20];
    const float* t_w3  = (const float*)d_in[21];
    const float* t_b3  = (const float*)d_in[22];
    const float* t_g3  = (const float*)d_in[23];
    const float* t_bb3 = (const float*)d_in[24];
    const float* t_w4  = (const float*)d_in[25];
    const float* t_b4  = (const float*)d_in[26];

    char* ws = (char*)d_ws;
    unsigned short* wsMT = (unsigned short*)(ws);              //  3,276,800
    unsigned short* wsWT = (unsigned short*)(ws +  3276800);   //  3,276,800
    float* ubs_acc       = (float*)         (ws +  6553600);   //    524,288
    unsigned short* Wt1  = (unsigned short*)(ws +  7077888);   //  2,686,976
    unsigned short* Wt2  = (unsigned short*)(ws +  9764864);   //  1,048,576
    unsigned short* Wt3  = (unsigned short*)(ws + 10813440);   //    262,144
    unsigned short* X    = (unsigned short*)(ws + 11075584);   //    671,744
    float*          C1   = (float*)         (ws + 11747328);   //  1,048,576
    unsigned short* H1   = (unsigned short*)(ws + 12795904);   //    524,288
    float*          C2   = (float*)         (ws + 13320192);   //    524,288
    unsigned short* H2   = (unsigned short*)(ws + 13844480);   //    262,144
    float*          C3   = (float*)         (ws + 14106624);   //    262,144 (end 14,368,768)
    // stats overlap the dead wsMT region (wsMT only read by attn, which has
    // completed before reduceX zeroes these and the gemms accumulate).
    float* stats1        = (float*)(ws);                       // 512 f32
    float* stats2        = (float*)(ws + 2048);                // 512 f32

    prologue_kernel<<<2480, 256, 0, stream>>>(q_w, k_w, v_w, lin_w, wsMT, wsWT,
                                              t_w1, t_w2, t_w3, Wt1, Wt2, Wt3, ubs_acc);
    attn_kernel<<<NCH_ * 32, 256, 0, stream>>>(ubs_feature, item_tables, wsMT, wsWT,
                                               lin_b, ln_g, ln_b, ubs_acc);
    reduceX_kernel<<<B_ + 1, 256, 0, stream>>>(ubs_acc, target_ad, profile_feature, context,
                                               item_tables, profile_tables, X, stats1);
    gemm_kernel<<<dim3(16, 16), 256, 0, stream>>>(X,  Wt1, t_b1, C1, 1312, 1024, stats1);
    lnapply_kernel<<<B_, 256, 0, stream>>>(C1, stats1, t_g1, t_bb1, H1, 1024, 1.f / 1024.f);
    gemm_kernel<<<dim3(8, 16),  256, 0, stream>>>(H1, Wt2, t_b2, C2, 1024, 512, stats2);
    lnapply_kernel<<<B_, 256, 0, stream>>>(C2, stats2, t_g2, t_bb2, H2, 512, 1.f / 512.f);
    gemm_kernel<<<dim3(4, 16),  256, 0, stream>>>(H2, Wt3, t_b3, C3, 512, 256, (float*)nullptr);
    final_kernel<<<B_, 256, 0, stream>>>(C3, t_g3, t_bb3, t_w4, t_b4, (float*)d_out);
}

// Round 5
// 255.816 us; speedup vs baseline: 1.3320x; 1.0383x over previous
//
#include <hip/hip_runtime.h>
#include <hip/hip_bf16.h>

#define B_ 256
#define L_ 100
#define F_ 8
#define P_ 4
#define E_ 64
#define H_ 4
#define D_ 64
#define C_ 32
#define V_ 10000
#define TOWER_IN_ 1312
#define LN_EPS 0.001f
#define LCH_ 4    // l's per attention block
#define NCH_ 25   // number of l-chunks
#define ZK_ 40    // padded k-stride for sZt (80B: 16B-aligned, conflict-free)

typedef __attribute__((ext_vector_type(8))) short bf8v;           // 8 bf16 (4 VGPRs)
typedef __attribute__((ext_vector_type(8))) unsigned short us8;   // 8 u16
typedef __attribute__((ext_vector_type(4))) float f4v;            // 4 f32 acc

__device__ __forceinline__ unsigned short f2bf(float x) {
    __hip_bfloat16 h = __float2bfloat16(x);
    return __builtin_bit_cast(unsigned short, h);
}

// raw barrier: LDS-drain + s_barrier, NO vmcnt drain (prefetch loads stay in flight)
#define BARRIER() do { \
    asm volatile("s_waitcnt lgkmcnt(0)" ::: "memory"); \
    __builtin_amdgcn_s_barrier(); \
    asm volatile("" ::: "memory"); \
} while (0)

// ---------------------------------------------------------------------------
// Kernel PRE: precomp (register-tiled f32) + ubs_acc zero.
//   blocks [0,400):  MT[l,h]=(Qh Kh^T)^T, WT[l,h]=(Vh Lh)^T -> bf16
//   blocks [400,528): zero ubs_acc
// ---------------------------------------------------------------------------
__global__ __launch_bounds__(256) void pre_kernel(
    const float* __restrict__ q_w, const float* __restrict__ k_w,
    const float* __restrict__ v_w, const float* __restrict__ lin_w,
    unsigned short* __restrict__ wsMT, unsigned short* __restrict__ wsWT,
    float* __restrict__ ubs_acc)
{
    __shared__ float sA[64][68];
    __shared__ float sB[64][68];
    const int t = threadIdx.x;
    const int bx = blockIdx.x;

    if (bx >= 400) {
        const int bi = bx - 400;                   // 128 blocks x 1024 floats
        float4 z = {0.f, 0.f, 0.f, 0.f};
        *(float4*)(ubs_acc + (size_t)bi * 1024 + t * 4) = z;
        return;
    }

    const int l = bx >> 2;
    const int h = bx & 3;
    const size_t obase = (size_t)(l * 4 + h) * 4096;
    const int te = t & 15, to = t >> 4;

    for (int i = 0; i < 16; ++i) {
        int idx = t + i * 256;
        int e = idx >> 6, d = idx & 63;
        sA[e][d] = q_w[(l * 64 + e) * 256 + h * 64 + d];
        sB[e][d] = k_w[(l * 64 + e) * 256 + h * 64 + d];
    }
    __syncthreads();
    {
        float acc[4][4];
        #pragma unroll
        for (int i = 0; i < 4; ++i)
            #pragma unroll
            for (int j = 0; j < 4; ++j) acc[i][j] = 0.f;
        for (int d0 = 0; d0 < 64; d0 += 4) {
            float4 a4[4], b4[4];
            #pragma unroll
            for (int i = 0; i < 4; ++i) a4[i] = *(const float4*)&sA[te + 16 * i][d0];
            #pragma unroll
            for (int j = 0; j < 4; ++j) b4[j] = *(const float4*)&sB[to + 16 * j][d0];
            #pragma unroll
            for (int i = 0; i < 4; ++i)
                #pragma unroll
                for (int j = 0; j < 4; ++j) {
                    acc[i][j] += a4[i].x * b4[j].x;
                    acc[i][j] += a4[i].y * b4[j].y;
                    acc[i][j] += a4[i].z * b4[j].z;
                    acc[i][j] += a4[i].w * b4[j].w;
                }
        }
        #pragma unroll
        for (int j = 0; j < 4; ++j)
            #pragma unroll
            for (int i = 0; i < 4; ++i)
                wsMT[obase + (to + 16 * j) * 64 + (te + 16 * i)] = f2bf(acc[i][j]);
    }
    __syncthreads();

    for (int i = 0; i < 16; ++i) {
        int idx = t + i * 256;
        int e = idx >> 6, d = idx & 63;
        sA[e][d] = v_w[(l * 64 + e) * 256 + h * 64 + d];
        int oo = idx & 63, dd = idx >> 6;
        sB[oo][dd] = lin_w[l * 16384 + (h * 64 + dd) * 64 + oo];
    }
    __syncthreads();
    {
        float acc[4][4];
        #pragma unroll
        for (int i = 0; i < 4; ++i)
            #pragma unroll
            for (int j = 0; j < 4; ++j) acc[i][j] = 0.f;
        for (int d0 = 0; d0 < 64; d0 += 4) {
            float4 a4[4], b4[4];
            #pragma unroll
            for (int i = 0; i < 4; ++i) a4[i] = *(const float4*)&sA[te + 16 * i][d0];
            #pragma unroll
            for (int j = 0; j < 4; ++j) b4[j] = *(const float4*)&sB[to + 16 * j][d0];
            #pragma unroll
            for (int i = 0; i < 4; ++i)
                #pragma unroll
                for (int j = 0; j < 4; ++j) {
                    acc[i][j] += a4[i].x * b4[j].x;
                    acc[i][j] += a4[i].y * b4[j].y;
                    acc[i][j] += a4[i].z * b4[j].z;
                    acc[i][j] += a4[i].w * b4[j].w;
                }
        }
        #pragma unroll
        for (int j = 0; j < 4; ++j)
            #pragma unroll
            for (int i = 0; i < 4; ++i)
                wsWT[obase + (to + 16 * j) * 64 + (te + 16 * i)] = f2bf(acc[i][j]);
    }
}

// ---------------------------------------------------------------------------
// Kernel A: fused attention (blocks < 800) + tower weight prep (blocks >= 800).
// attn logic unchanged from R1/R3.  prep hides under attn's tail.
// ---------------------------------------------------------------------------
__global__ __launch_bounds__(256, 3) void attn_kernel(
    const int* __restrict__ ubs_feature, const float* __restrict__ item_tables,
    const unsigned short* __restrict__ wsMT, const unsigned short* __restrict__ wsWT,
    const float* __restrict__ lin_b, const float* __restrict__ ln_g,
    const float* __restrict__ ln_b, float* __restrict__ ubs_acc,
    const float* __restrict__ w1, const float* __restrict__ w2,
    const float* __restrict__ w3,
    unsigned short* __restrict__ Wt1, unsigned short* __restrict__ Wt2,
    unsigned short* __restrict__ Wt3)
{
    __shared__ __align__(16) unsigned short sUE[64][72];       // rows=b_loc*8+f
    __shared__ __align__(16) unsigned short sT[64][136];       // cols=hl*64+e'
    __shared__ __align__(16) unsigned short sZt[4][64][ZK_];   // [pair][e][k] (k<32 used)
    __shared__ __align__(16) unsigned short sAblk[4][16][32];  // [pair][r][k]
    __shared__ float sLng[64], sLnb[64], sLinb[LCH_][64];

    const int t = threadIdx.x;

    if (blockIdx.x >= 800) {
        // ---------------- prep (weight transpose) ----------------
        float (*tile)[33] = (float (*)[33])sT;   // 32x33 f32 fits in sT region
        int bi = blockIdx.x - 800;
        const float* src; unsigned short* dst; int K, N, tk, tn;
        if (bi < 1312)      { src = w1; dst = Wt1; K = 1312; N = 1024; tk = bi / 32;  tn = bi % 32; }
        else if (bi < 1824) { int i = bi - 1312; src = w2; dst = Wt2; K = 1024; N = 512; tk = i / 16; tn = i % 16; }
        else                { int i = bi - 1824; src = w3; dst = Wt3; K = 512;  N = 256; tk = i / 8;  tn = i % 8; }
        const int k0 = tk * 32, n0 = tn * 32;
        const int rr = t >> 5, cc = t & 31;
        #pragma unroll
        for (int i = 0; i < 4; ++i) {
            int r = rr * 4 + i;
            tile[r][cc] = src[(size_t)(k0 + r) * N + n0 + cc];
        }
        __syncthreads();
        #pragma unroll
        for (int i = 0; i < 4; ++i) {
            int r = rr * 4 + i;
            dst[(size_t)(n0 + r) * K + k0 + cc] = f2bf(tile[cc][r]);
        }
        return;
    }

    const int c = blockIdx.x >> 5;            // l-chunk 0..24
    const int b0 = (blockIdx.x & 31) * 8;
    const int wv = t >> 6, lane = t & 63, quad = lane >> 4, cl = lane & 15;
    const int role = wv >> 1, hlw = wv & 1;

    const int grow = wv * 16 + (lane >> 2);   // row in [0,64) = b_loc*8 + f
    const int gseg = lane & 3;                // 16-float segment
    const int gb = b0 + (grow >> 3), gf = grow & 7;

    if (t < 64) { sLng[t] = ln_g[t]; sLnb[t] = ln_b[t]; }
    if (t >= 64 && t < 128) {
        #pragma unroll
        for (int li = 0; li < LCH_; ++li)
            sLinb[li][t - 64] = lin_b[(c * LCH_ + li) * 64 + (t - 64)];
    }

    int vidx[LCH_];
    #pragma unroll
    for (int li = 0; li < LCH_; ++li)
        vidx[li] = ubs_feature[(gb * L_ + c * LCH_ + li) * F_ + gf];

    float4 pf[4];
    bf8v bfrag[4][2];

    auto load_bfrag = [&](int lh) {   // lh = l*4 + half*2 + hlw
        const unsigned short* Bsrc = (role == 0 ? wsMT : wsWT) + ((size_t)lh * 4096);
        #pragma unroll
        for (int nt = 0; nt < 4; ++nt)
            #pragma unroll
            for (int k2 = 0; k2 < 2; ++k2)
                bfrag[nt][k2] = *(const bf8v*)(Bsrc + (nt * 16 + cl) * 64 + k2 * 32 + quad * 8);
    };
    auto load_pf = [&](int li) {
        const float* srcp = item_tables + ((size_t)gf * V_ + vidx[li]) * 64 + gseg * 16;
        #pragma unroll
        for (int j = 0; j < 4; ++j) pf[j] = ((const float4*)srcp)[j];
    };
    auto store_ue = [&]() {
        us8 u0, u1;
        u0[0] = f2bf(pf[0].x); u0[1] = f2bf(pf[0].y); u0[2] = f2bf(pf[0].z); u0[3] = f2bf(pf[0].w);
        u0[4] = f2bf(pf[1].x); u0[5] = f2bf(pf[1].y); u0[6] = f2bf(pf[1].z); u0[7] = f2bf(pf[1].w);
        u1[0] = f2bf(pf[2].x); u1[1] = f2bf(pf[2].y); u1[2] = f2bf(pf[2].z); u1[3] = f2bf(pf[2].w);
        u1[4] = f2bf(pf[3].x); u1[5] = f2bf(pf[3].y); u1[6] = f2bf(pf[3].z); u1[7] = f2bf(pf[3].w);
        *(us8*)&sUE[grow][gseg * 16]     = u0;
        *(us8*)&sUE[grow][gseg * 16 + 8] = u1;
    };

    load_pf(0);
    load_bfrag((c * LCH_) * 4 + hlw);
    store_ue();
    BARRIER();

    float lnacc[16];
    #pragma unroll
    for (int i = 0; i < 16; ++i) lnacc[i] = 0.f;

    for (int li = 0; li < LCH_; ++li) {
        const int l = c * LCH_ + li;

        if (li + 1 < LCH_) load_pf(li + 1);

        f4v accO[4];
        #pragma unroll
        for (int nt = 0; nt < 4; ++nt) accO[nt] = {0.f, 0.f, 0.f, 0.f};

        #pragma unroll
        for (int half = 0; half < 2; ++half) {
            #pragma unroll
            for (int m = 0; m < 4; ++m) {
                bf8v a0 = *(const bf8v*)&sUE[m * 16 + cl][quad * 8];
                bf8v a1 = *(const bf8v*)&sUE[m * 16 + cl][32 + quad * 8];
                #pragma unroll
                for (int nt = 0; nt < 4; ++nt) {
                    f4v acc = {0.f, 0.f, 0.f, 0.f};
                    acc = __builtin_amdgcn_mfma_f32_16x16x32_bf16(a0, bfrag[nt][0], acc, 0, 0, 0);
                    acc = __builtin_amdgcn_mfma_f32_16x16x32_bf16(a1, bfrag[nt][1], acc, 0, 0, 0);
                    if (role == 0) {
                        #pragma unroll
                        for (int j = 0; j < 4; ++j)
                            sT[m * 16 + quad * 4 + j][hlw * 64 + nt * 16 + cl] = f2bf(acc[j]);
                    } else {
                        ushort4 zp;
                        zp.x = f2bf(acc[0]); zp.y = f2bf(acc[1]);
                        zp.z = f2bf(acc[2]); zp.w = f2bf(acc[3]);
                        const int k0 = (quad >> 1) * 16 + hlw * 8 + (quad & 1) * 4;
                        *(ushort4*)&sZt[m][nt * 16 + cl][k0] = zp;
                    }
                }
            }
            if (half == 0)            load_bfrag(l * 4 + 2 + hlw);
            else if (li + 1 < LCH_)   load_bfrag((l + 1) * 4 + hlw);
            BARRIER();

            {
                const int p = wv;
                const bool valid = (cl >> 3) == (quad >> 1);
                #pragma unroll
                for (int hl = 0; hl < 2; ++hl) {
                    bf8v a0s = *(const bf8v*)&sT[p * 16 + cl][hl * 64 + quad * 8];
                    bf8v a1s = *(const bf8v*)&sT[p * 16 + cl][hl * 64 + 32 + quad * 8];
                    bf8v u0 = *(const bf8v*)&sUE[p * 16 + cl][quad * 8];
                    bf8v u1 = *(const bf8v*)&sUE[p * 16 + cl][32 + quad * 8];
                    f4v acc = {0.f, 0.f, 0.f, 0.f};
                    acc = __builtin_amdgcn_mfma_f32_16x16x32_bf16(a0s, u0, acc, 0, 0, 0);
                    acc = __builtin_amdgcn_mfma_f32_16x16x32_bf16(a1s, u1, acc, 0, 0, 0);
                    const int kk = hl * 8 + (cl & 7) + (cl >> 3) * 16;
                    #pragma unroll
                    for (int j = 0; j < 4; ++j) {
                        float v = acc[j] * 0.125f;
                        float mx = v;
                        mx = fmaxf(mx, __shfl_xor(mx, 1));
                        mx = fmaxf(mx, __shfl_xor(mx, 2));
                        mx = fmaxf(mx, __shfl_xor(mx, 4));
                        float ex = __expf(v - mx);
                        float sm = ex;
                        sm += __shfl_xor(sm, 1);
                        sm += __shfl_xor(sm, 2);
                        sm += __shfl_xor(sm, 4);
                        float aw = valid ? ex * __builtin_amdgcn_rcpf(sm) : 0.f;
                        sAblk[p][quad * 4 + j][kk] = f2bf(aw);
                    }
                }
            }

            {
                const int p = wv;
                bf8v a0p = *(const bf8v*)&sAblk[p][cl][quad * 8];
                #pragma unroll
                for (int nt = 0; nt < 4; ++nt) {
                    bf8v bz = *(const bf8v*)&sZt[p][nt * 16 + cl][quad * 8];
                    accO[nt] = __builtin_amdgcn_mfma_f32_16x16x32_bf16(a0p, bz, accO[nt], 0, 0, 0);
                }
            }
            BARRIER();
        }

        {
            float x[16];
            #pragma unroll
            for (int nt = 0; nt < 4; ++nt)
                #pragma unroll
                for (int j = 0; j < 4; ++j)
                    x[nt * 4 + j] = accO[nt][j] + sLinb[li][nt * 16 + cl];
            #pragma unroll
            for (int j = 0; j < 4; ++j) {
                float s = x[j] + x[4 + j] + x[8 + j] + x[12 + j];
                #pragma unroll
                for (int m = 1; m < 16; m <<= 1) s += __shfl_xor(s, m);
                float mean = s * (1.f / 64.f);
                float q = 0.f;
                #pragma unroll
                for (int nt = 0; nt < 4; ++nt) { float d = x[nt * 4 + j] - mean; q += d * d; }
                #pragma unroll
                for (int m = 1; m < 16; m <<= 1) q += __shfl_xor(q, m);
                float rst = rsqrtf(q * (1.f / 64.f) + LN_EPS);
                #pragma unroll
                for (int nt = 0; nt < 4; ++nt) {
                    int col = nt * 16 + cl;
                    lnacc[nt * 4 + j] += (x[nt * 4 + j] - mean) * rst * sLng[col] + sLnb[col];
                }
            }
        }

        if (li + 1 < LCH_) {
            store_ue();
            BARRIER();
        }
    }

    #pragma unroll
    for (int j = 0; j < 4; ++j) {
        const int row = wv * 16 + quad * 4 + j;
        const int b = b0 + (row >> 3), f = row & 7;
        #pragma unroll
        for (int nt = 0; nt < 4; ++nt)
            atomicAdd(&ubs_acc[(size_t)b * 512 + f * 64 + nt * 16 + cl], lnacc[nt * 4 + j]);
    }
}

// ---------------------------------------------------------------------------
// gemm core: C[m0..+16][n0..+64] += LDS-A . Bw^T + bias.  4 waves, 16 col/wave.
// ---------------------------------------------------------------------------
__device__ __forceinline__ void gemm_from_lds(
    const unsigned short* sA, int lda,
    const unsigned short* __restrict__ Bw, const float* __restrict__ bias,
    float* __restrict__ Cd, int K, int N, int n0w, int m0,
    int quad, int cl)
{
    f4v acc0 = {0.f, 0.f, 0.f, 0.f};
    f4v acc1 = {0.f, 0.f, 0.f, 0.f};
    const unsigned short* arow = sA + cl * lda + quad * 8;
    const unsigned short* brow = Bw + (size_t)(n0w + cl) * K + quad * 8;
    int k0 = 0;
    for (; k0 + 64 <= K; k0 += 64) {
        bf8v a0 = *(const bf8v*)(arow + k0);
        bf8v b0 = *(const bf8v*)(brow + k0);
        bf8v a1 = *(const bf8v*)(arow + k0 + 32);
        bf8v b1 = *(const bf8v*)(brow + k0 + 32);
        acc0 = __builtin_amdgcn_mfma_f32_16x16x32_bf16(a0, b0, acc0, 0, 0, 0);
        acc1 = __builtin_amdgcn_mfma_f32_16x16x32_bf16(a1, b1, acc1, 0, 0, 0);
    }
    if (k0 < K) {
        bf8v a = *(const bf8v*)(arow + k0);
        bf8v b = *(const bf8v*)(brow + k0);
        acc0 = __builtin_amdgcn_mfma_f32_16x16x32_bf16(a, b, acc0, 0, 0, 0);
    }
    float bv = bias[n0w + cl];
    #pragma unroll
    for (int j = 0; j < 4; ++j)
        Cd[(size_t)(m0 + quad * 4 + j) * N + n0w + cl] = acc0[j] + acc1[j] + bv;
}

// ---------------------------------------------------------------------------
// LN-from-C into LDS bf16 (per-block, 16 rows, N cols).  row = t>>4, sub = t&15.
// NC4 = N/64 float4-chunks per thread.
// ---------------------------------------------------------------------------
__device__ __forceinline__ void ln_rows_to_lds(
    const float* __restrict__ Cd, int N, int m0,
    const float* __restrict__ g, const float* __restrict__ bb,
    unsigned short* sH, int lda, int t, float invN)
{
    const int r = t >> 4, sub = t & 15;
    const float* crow = Cd + (size_t)(m0 + r) * N;
    float s = 0.f, s2 = 0.f;
    for (int j = sub * 4; j < N; j += 64) {
        float4 x = *(const float4*)(crow + j);
        s  += x.x + x.y + x.z + x.w;
        s2 += x.x * x.x + x.y * x.y + x.z * x.z + x.w * x.w;
    }
    #pragma unroll
    for (int m = 1; m < 16; m <<= 1) { s += __shfl_xor(s, m); s2 += __shfl_xor(s2, m); }
    const float mean = s * invN;
    const float var  = s2 * invN - mean * mean;
    const float rst  = rsqrtf(fmaxf(var, 0.f) + LN_EPS);
    for (int j = sub * 4; j < N; j += 64) {
        float4 x = *(const float4*)(crow + j);
        ushort4 o;
        o.x = f2bf(fmaxf((x.x - mean) * rst * g[j]     + bb[j],     0.f));
        o.y = f2bf(fmaxf((x.y - mean) * rst * g[j + 1] + bb[j + 1], 0.f));
        o.z = f2bf(fmaxf((x.z - mean) * rst * g[j + 2] + bb[j + 2], 0.f));
        o.w = f2bf(fmaxf((x.w - mean) * rst * g[j + 3] + bb[j + 3], 0.f));
        *(ushort4*)&sH[r * lda + j] = o;
    }
}

// ---------------------------------------------------------------------------
// Kernel G1: X-build (LDS) + gemm1 -> C1 f32.  grid (16 n x 16 m) = 256 blocks.
// ---------------------------------------------------------------------------
#define XLD 1320
__global__ __launch_bounds__(256) void gemm1x_kernel(
    const float* __restrict__ ubs_acc,
    const int* __restrict__ target_ad, const int* __restrict__ profile_feature,
    const float* __restrict__ context,
    const float* __restrict__ item_tables, const float* __restrict__ profile_tables,
    const unsigned short* __restrict__ Wt1, const float* __restrict__ b1,
    float* __restrict__ C1)
{
    __shared__ __align__(16) unsigned short sX[16][XLD];
    const int t = threadIdx.x;
    const int wv = t >> 6, lane = t & 63, quad = lane >> 4, cl = lane & 15;
    const int m0 = (blockIdx.x >> 4) * 16;
    const int n0w = (blockIdx.x & 15) * 64 + wv * 16;

    // build X rows m0..m0+15: row = t>>4, cols sub*4 + k*64
    {
        const int r = t >> 4, sub = t & 15;
        const int gb = m0 + r;
        #pragma unroll
        for (int k = 0; k < 21; ++k) {
            int cc = sub * 4 + k * 64;
            if (cc >= TOWER_IN_) break;
            float4 x;
            if (cc < 512) {
                x = *(const float4*)(ubs_acc + (size_t)gb * 512 + cc);
                x.x = fmaxf(x.x * 0.01f, 0.f); x.y = fmaxf(x.y * 0.01f, 0.f);
                x.z = fmaxf(x.z * 0.01f, 0.f); x.w = fmaxf(x.w * 0.01f, 0.f);
            } else if (cc < 1024) {
                int f = (cc - 512) >> 6, e = (cc - 512) & 63;
                x = *(const float4*)(item_tables + ((size_t)f * V_ + target_ad[gb * 8 + f]) * 64 + e);
            } else if (cc < 1280) {
                int pp = (cc - 1024) >> 6, e = (cc - 1024) & 63;
                x = *(const float4*)(profile_tables + ((size_t)pp * V_ + profile_feature[gb * 4 + pp]) * 64 + e);
            } else {
                x = *(const float4*)(context + (size_t)gb * 32 + (cc - 1280));
            }
            ushort4 o;
            o.x = f2bf(x.x); o.y = f2bf(x.y); o.z = f2bf(x.z); o.w = f2bf(x.w);
            *(ushort4*)&sX[r][cc] = o;
        }
    }
    __syncthreads();
    gemm_from_lds(&sX[0][0], XLD, Wt1, b1, C1, 1312, 1024, n0w, m0, quad, cl);
}

// ---------------------------------------------------------------------------
// Kernel G2: LN1(C1)+ReLU (LDS) + gemm2 -> C2 f32.  grid (8 n x 16 m) = 128.
// ---------------------------------------------------------------------------
#define H1LD 1032
__global__ __launch_bounds__(256) void gemm2f_kernel(
    const float* __restrict__ C1, const float* __restrict__ g1,
    const float* __restrict__ bb1,
    const unsigned short* __restrict__ Wt2, const float* __restrict__ b2,
    float* __restrict__ C2)
{
    __shared__ __align__(16) unsigned short sH[16][H1LD];
    const int t = threadIdx.x;
    const int wv = t >> 6, lane = t & 63, quad = lane >> 4, cl = lane & 15;
    const int m0 = (blockIdx.x >> 3) * 16;
    const int n0w = (blockIdx.x & 7) * 64 + wv * 16;

    ln_rows_to_lds(C1, 1024, m0, g1, bb1, &sH[0][0], H1LD, t, 1.f / 1024.f);
    __syncthreads();
    gemm_from_lds(&sH[0][0], H1LD, Wt2, b2, C2, 1024, 512, n0w, m0, quad, cl);
}

// ---------------------------------------------------------------------------
// Kernel G3: LN2(C2)+ReLU (LDS) + gemm3 (full 256-col rows) + LN3 + ReLU +
// dot(w4) + sigmoid -> out.  grid = 16 blocks (16 rows each), 256 threads.
// ---------------------------------------------------------------------------
#define H2LD 520
__global__ __launch_bounds__(256) void gemm3f_kernel(
    const float* __restrict__ C2, const float* __restrict__ g2,
    const float* __restrict__ bb2,
    const unsigned short* __restrict__ Wt3, const float* __restrict__ b3,
    const float* __restrict__ g3, const float* __restrict__ bb3,
    const float* __restrict__ w4, const float* __restrict__ b4,
    float* __restrict__ out)
{
    __shared__ __align__(16) unsigned short sH[16][H2LD];
    __shared__ float sS[4][16], sQ[4][16], sP[4][16];
    const int t = threadIdx.x;
    const int wv = t >> 6, lane = t & 63, quad = lane >> 4, cl = lane & 15;
    const int m0 = blockIdx.x * 16;

    ln_rows_to_lds(C2, 512, m0, g2, bb2, &sH[0][0], H2LD, t, 1.f / 512.f);
    __syncthreads();

    // gemm3: wave wv covers cols [wv*64, wv*64+64) via 4 nt sub-tiles, K=512
    f4v acc[4];
    #pragma unroll
    for (int nt = 0; nt < 4; ++nt) acc[nt] = {0.f, 0.f, 0.f, 0.f};
    for (int k0 = 0; k0 < 512; k0 += 32) {
        bf8v a = *(const bf8v*)&sH[cl][k0 + quad * 8];
        #pragma unroll
        for (int nt = 0; nt < 4; ++nt) {
            const int col0 = wv * 64 + nt * 16;
            bf8v b = *(const bf8v*)(Wt3 + (size_t)(col0 + cl) * 512 + k0 + quad * 8);
            acc[nt] = __builtin_amdgcn_mfma_f32_16x16x32_bf16(a, b, acc[nt], 0, 0, 0);
        }
    }
    #pragma unroll
    for (int nt = 0; nt < 4; ++nt) {
        float bv = b3[wv * 64 + nt * 16 + cl];
        #pragma unroll
        for (int j = 0; j < 4; ++j) acc[nt][j] += bv;
    }

    // LN3 stats: per row r = quad*4+j over 256 cols
    #pragma unroll
    for (int j = 0; j < 4; ++j) {
        float s = acc[0][j] + acc[1][j] + acc[2][j] + acc[3][j];
        float q = acc[0][j]*acc[0][j] + acc[1][j]*acc[1][j] + acc[2][j]*acc[2][j] + acc[3][j]*acc[3][j];
        #pragma unroll
        for (int m = 1; m < 16; m <<= 1) { s += __shfl_xor(s, m); q += __shfl_xor(q, m); }
        if (cl == 0) { sS[wv][quad * 4 + j] = s; sQ[wv][quad * 4 + j] = q; }
    }
    __syncthreads();
    float meanr[4], rstdr[4];
    #pragma unroll
    for (int j = 0; j < 4; ++j) {
        const int row = quad * 4 + j;
        float s = sS[0][row] + sS[1][row] + sS[2][row] + sS[3][row];
        float q = sQ[0][row] + sQ[1][row] + sQ[2][row] + sQ[3][row];
        float mean = s * (1.f / 256.f);
        float var  = q * (1.f / 256.f) - mean * mean;
        meanr[j] = mean;
        rstdr[j] = rsqrtf(fmaxf(var, 0.f) + LN_EPS);
    }

    // h = relu(LN3), partial dot with w4
    #pragma unroll
    for (int j = 0; j < 4; ++j) {
        float p = 0.f;
        #pragma unroll
        for (int nt = 0; nt < 4; ++nt) {
            const int col = wv * 64 + nt * 16 + cl;
            float h = fmaxf((acc[nt][j] - meanr[j]) * rstdr[j] * g3[col] + bb3[col], 0.f);
            p += h * w4[col];
        }
        #pragma unroll
        for (int m = 1; m < 16; m <<= 1) p += __shfl_xor(p, m);
        if (cl == 0) sP[wv][quad * 4 + j] = p;
    }
    __syncthreads();
    if (t < 16) {
        float p = sP[0][t] + sP[1][t] + sP[2][t] + sP[3][t];
        out[m0 + t] = 1.f / (1.f + expf(-(p + b4[0])));
    }
}

// ---------------------------------------------------------------------------
extern "C" void kernel_launch(void* const* d_in, const int* in_sizes, int n_in,
                              void* d_out, int out_size, void* d_ws, size_t ws_size,
                              hipStream_t stream)
{
    (void)in_sizes; (void)n_in; (void)out_size; (void)ws_size;
    const int*   target_ad       = (const int*)d_in[0];
    const int*   ubs_feature     = (const int*)d_in[1];
    const int*   profile_feature = (const int*)d_in[2];
    const float* context         = (const float*)d_in[3];
    const float* item_tables     = (const float*)d_in[4];
    const float* profile_tables  = (const float*)d_in[5];
    const float* q_w   = (const float*)d_in[6];
    const float* k_w   = (const float*)d_in[7];
    const float* v_w   = (const float*)d_in[8];
    const float* lin_w = (const float*)d_in[9];
    const float* lin_b = (const float*)d_in[10];
    const float* ln_g  = (const float*)d_in[11];
    const float* ln_b  = (const float*)d_in[12];
    const float* t_w1  = (const float*)d_in[13];
    const float* t_b1  = (const float*)d_in[14];
    const float* t_g1  = (const float*)d_in[15];
    const float* t_bb1 = (const float*)d_in[16];
    const float* t_w2  = (const float*)d_in[17];
    const float* t_b2  = (const float*)d_in[18];
    const float* t_g2  = (const float*)d_in[19];
    const float* t_bb2 = (const float*)d_in[20];
    const float* t_w3  = (const float*)d_in[21];
    const float* t_b3  = (const float*)d_in[22];
    const float* t_g3  = (const float*)d_in[23];
    const float* t_bb3 = (const float*)d_in[24];
    const float* t_w4  = (const float*)d_in[25];
    const float* t_b4  = (const float*)d_in[26];

    char* ws = (char*)d_ws;
    unsigned short* wsMT = (unsigned short*)(ws);              //  3,276,800
    unsigned short* wsWT = (unsigned short*)(ws +  3276800);   //  3,276,800
    float* ubs_acc       = (float*)         (ws +  6553600);   //    524,288
    unsigned short* Wt1  = (unsigned short*)(ws +  7077888);   //  2,686,976
    unsigned short* Wt2  = (unsigned short*)(ws +  9764864);   //  1,048,576
    unsigned short* Wt3  = (unsigned short*)(ws + 10813440);   //    262,144
    float*          C1   = (float*)         (ws + 11075584);   //  1,048,576
    float*          C2   = (float*)         (ws + 12124160);   //    524,288 (end 12,648,448)

    pre_kernel<<<528, 256, 0, stream>>>(q_w, k_w, v_w, lin_w, wsMT, wsWT, ubs_acc);
    attn_kernel<<<800 + 1952, 256, 0, stream>>>(ubs_feature, item_tables, wsMT, wsWT,
                                                lin_b, ln_g, ln_b, ubs_acc,
                                                t_w1, t_w2, t_w3, Wt1, Wt2, Wt3);
    gemm1x_kernel<<<256, 256, 0, stream>>>(ubs_acc, target_ad, profile_feature, context,
                                           item_tables, profile_tables, Wt1, t_b1, C1);
    gemm2f_kernel<<<128, 256, 0, stream>>>(C1, t_g1, t_bb1, Wt2, t_b2, C2);
    gemm3f_kernel<<<16, 256, 0, stream>>>(C2, t_g2, t_bb2, Wt3, t_b3,
                                          t_g3, t_bb3, t_w4, t_b4, (float*)d_out);
}